// Round 8
// baseline (933.605 us; speedup 1.0000x reference)
//
#include <hip/hip_runtime.h>
#include <hip/hip_bf16.h>

typedef __hip_bfloat16 bf16;

// ---- adaptive loads: fb=1 -> bf16 data, fb=0 -> float32 data ----
__device__ __forceinline__ float ldf(const void* p, int fb, size_t i) {
    if (fb) {
        unsigned int u = ((const unsigned short*)p)[i];
        return __uint_as_float(u << 16);
    }
    return ((const float*)p)[i];
}
// fi=1 -> int64 underlying (read low word), fi=0 -> int32. Clamped to [0,n).
__device__ __forceinline__ int ldi(const int* p, int fi, size_t i, int n) {
    int v = fi ? p[2 * i] : p[i];
    return ((unsigned)v < (unsigned)n) ? v : 0;
}
__device__ __forceinline__ float bf2f_bits(unsigned short u) {
    return __uint_as_float(((unsigned int)u) << 16);
}

// ---------------- dtype detection ----------------
__global__ void k_detect(const void* x, const int* ei, int* flags) {
    if (threadIdx.x == 0 && blockIdx.x == 0) {
        const unsigned short* u = (const unsigned short*)x;
        int bad = 0;
        for (int i = 0; i < 128; ++i) {
            float v = bf2f_bits(u[i]);
            if (!(v > -64.f && v < 64.f)) bad++;  // NaN fails both
        }
        flags[0] = (bad >= 4) ? 0 : 1;  // 1 = floats are bf16
        int nz = 0;
        for (int i = 0; i < 64; ++i) nz |= ei[2 * i + 1];
        flags[1] = (nz == 0) ? 1 : 0;   // 1 = indices are int64
    }
}

__global__ void k_sentinel(float* out, int nfloats) {
    int i = blockIdx.x * blockDim.x + threadIdx.x;
    if (i < nfloats) out[i] = 1000.0f;
}

// ---------------- CSR build ----------------
__global__ void k_zero(int* counts, int n1) {
    int i = blockIdx.x * blockDim.x + threadIdx.x;
    if (i < n1) counts[i] = 0;
}

__global__ void k_hist(const int* __restrict__ ei, const int* __restrict__ flags,
                       int* counts, int E, int n) {
    int e = blockIdx.x * blockDim.x + threadIdx.x;
    if (e >= E) return;
    int c = ldi(ei, flags[1], (size_t)E + e, n);
    atomicAdd(&counts[c], 1);
}

// chunk = 512. scan1: per-chunk exclusive scan into rowptr; also dinv (fused).
__global__ void k_scan1(const int* __restrict__ counts, int* __restrict__ rowptr,
                        int* __restrict__ chsum, float* __restrict__ dinv, int n) {
    __shared__ int s[512];
    int t = threadIdx.x, i = blockIdx.x * 512 + t;
    int v = (i < n) ? counts[i] : 0;
    if (i < n) dinv[i] = rsqrtf((float)(v + 1));  // +1 self loop
    s[t] = v;
    __syncthreads();
    for (int off = 1; off < 512; off <<= 1) {
        int add = (t >= off) ? s[t - off] : 0;
        __syncthreads();
        s[t] += add;
        __syncthreads();
    }
    if (i < n) rowptr[i] = s[t] - v;            // chunk-local exclusive
    if (t == 511) chsum[blockIdx.x] = s[511];   // chunk total
}

// scan2: one block scans <=256 chunk sums (exclusive, in place)
__global__ void k_scan2(int* chsum, int nch) {
    __shared__ int s[256];
    int t = threadIdx.x;
    int v = (t < nch) ? chsum[t] : 0;
    s[t] = v;
    __syncthreads();
    for (int off = 1; off < 256; off <<= 1) {
        int add = (t >= off) ? s[t - off] : 0;
        __syncthreads();
        s[t] += add;
        __syncthreads();
    }
    if (t < nch) chsum[t] = s[t] - v;           // exclusive
}

// scan3: add chunk offsets; write cursor copy into counts; rowptr[n]=E
__global__ void k_scan3(int* __restrict__ rowptr, const int* __restrict__ chsum,
                        int* __restrict__ counts, int n, int E) {
    int t = threadIdx.x, i = blockIdx.x * 512 + t;
    if (i < n) {
        int val = rowptr[i] + chsum[blockIdx.x];
        rowptr[i] = val;
        counts[i] = val;  // cursor
    }
    if (blockIdx.x == 0 && t == 0) rowptr[n] = E;
}

__global__ void k_fill(const int* __restrict__ ei, const int* __restrict__ flags,
                       int* __restrict__ cursor, int* __restrict__ srcs, int E, int n) {
    int e = blockIdx.x * blockDim.x + threadIdx.x;
    if (e >= E) return;
    int fi = flags[1];
    int r = ldi(ei, fi, e, n);
    int c = ldi(ei, fi, (size_t)E + e, n);
    int pos = atomicAdd(&cursor[c], 1);
    srcs[pos] = r;
}

// ---------------- fused node stage 1: gather x + h1 MLP + xw2 ----------------
// 32 lanes per node: gather over neighbors parallelized across lanes (deg/32
// iterations), butterfly-reduce, then lane j computes xw2[:,j].
__global__ void k_node1(const void* __restrict__ x, const int* __restrict__ flags,
                        const float* __restrict__ dinv, const int* __restrict__ rowptr,
                        const int* __restrict__ srcs,
                        const void* __restrict__ W1, const void* __restrict__ b1,
                        const void* __restrict__ W2,
                        unsigned short* __restrict__ xw2, int n) {
    __shared__ float sW1[128];
    __shared__ float sb1[64];
    __shared__ float sW2[64 * 32];
    int tid = threadIdx.x;
    int fb = flags[0];
    for (int idx = tid; idx < 128; idx += blockDim.x) sW1[idx] = ldf(W1, fb, idx);
    for (int idx = tid; idx < 64; idx += blockDim.x)  sb1[idx] = ldf(b1, fb, idx);
    for (int idx = tid; idx < 64 * 32; idx += blockDim.x) sW2[idx] = ldf(W2, fb, idx);
    __syncthreads();
    int t = blockIdx.x * blockDim.x + tid;
    int i = t >> 5, lane = t & 31;
    if (i >= n) return;
    int start = rowptr[i], end = rowptr[i + 1];
    float di = dinv[i];
    float p0 = 0.f, p1 = 0.f;
    if (fb) {
        const unsigned int* xu = (const unsigned int*)x;  // one row = one dword
        for (int m = start + lane; m < end; m += 32) {
            int r = srcs[m];
            float dr = dinv[r];
            unsigned int w = xu[r];
            p0 = fmaf(dr, __uint_as_float(w << 16), p0);
            p1 = fmaf(dr, __uint_as_float(w & 0xffff0000u), p1);
        }
    } else {
        const float2* xf = (const float2*)x;
        for (int m = start + lane; m < end; m += 32) {
            int r = srcs[m];
            float dr = dinv[r];
            float2 xv = xf[r];
            p0 = fmaf(dr, xv.x, p0);
            p1 = fmaf(dr, xv.y, p1);
        }
    }
#pragma unroll
    for (int off = 16; off; off >>= 1) {
        p0 += __shfl_xor(p0, off, 32);
        p1 += __shfl_xor(p1, off, 32);
    }
    float xi0, xi1;
    if (fb) {
        unsigned int w = ((const unsigned int*)x)[i];
        xi0 = __uint_as_float(w << 16);
        xi1 = __uint_as_float(w & 0xffff0000u);
    } else {
        float2 xv = ((const float2*)x)[i];
        xi0 = xv.x; xi1 = xv.y;
    }
    float a0 = di * fmaf(di, xi0, p0);
    float a1 = di * fmaf(di, xi1, p1);
    int j = lane;
    float s = 0.f;
#pragma unroll 4
    for (int k = 0; k < 64; ++k) {
        float h = fmaxf(fmaf(a0, sW1[k], fmaf(a1, sW1[64 + k], sb1[k])), 0.f);
        s = fmaf(h, sW2[k * 32 + j], s);
    }
    xw2[t] = (unsigned short)(__float_as_uint(s) >> 16);
}

// ---------------- layer-2 aggregation (gather), h2 dtype templated ----------------
template <int H2F>
__global__ void k_gather2(const unsigned short* __restrict__ xw2, const int* __restrict__ flags,
                          const float* __restrict__ dinv, const int* __restrict__ rowptr,
                          const int* __restrict__ srcs, const void* __restrict__ b2v,
                          void* __restrict__ h2, int n) {
    int t = blockIdx.x * blockDim.x + threadIdx.x;
    int i = t >> 5, k = t & 31;
    if (i >= n) return;
    float di = dinv[i];
    float acc = di * bf2f_bits(xw2[i * 32 + k]);
    int mend = rowptr[i + 1];
    for (int m = rowptr[i]; m < mend; ++m) {
        int r = srcs[m];
        acc = fmaf(dinv[r], bf2f_bits(xw2[r * 32 + k]), acc);
    }
    float v = fmaxf(fmaf(di, acc, ldf(b2v, flags[0], k)), 0.f);
    if (H2F) ((float*)h2)[t] = v;
    else     ((unsigned short*)h2)[t] = (unsigned short)(__float_as_uint(v) >> 16);
}

// ---------------- edge MLP: 16 lanes/edge, grid-stride ----------------
#define ACC8(A, WA, WB)                                                              \
    accj += __uint_as_float((A).x << 16) * (WA).x                                    \
          + __uint_as_float((A).x & 0xffff0000u) * (WA).y                            \
          + __uint_as_float((A).y << 16) * (WA).z                                    \
          + __uint_as_float((A).y & 0xffff0000u) * (WA).w                            \
          + __uint_as_float((A).z << 16) * (WB).x                                    \
          + __uint_as_float((A).z & 0xffff0000u) * (WB).y                            \
          + __uint_as_float((A).w << 16) * (WB).z                                    \
          + __uint_as_float((A).w & 0xffff0000u) * (WB).w;

// fp32 path: float2 pair accumulation (pk_fma-friendly), no unpacks
#define PK4(V, W)                                                                    \
    ac0 = fmaf((V).x, (W).x, ac0); ac1 = fmaf((V).y, (W).y, ac1);                    \
    ac0 = fmaf((V).z, (W).z, ac0); ac1 = fmaf((V).w, (W).w, ac1);

template <int H2F>
__global__ void k_edge_mlp(const int* __restrict__ ei, const int* __restrict__ flags,
                           const void* __restrict__ h2, const void* __restrict__ ea,
                           const void* __restrict__ Wm1, const void* __restrict__ bm1,
                           const void* __restrict__ Wm2, const void* __restrict__ bm2,
                           void* __restrict__ out, int E, int n) {
    // sWt: Wm1 transposed, column-major: sWt[j*68 + row] = Wm1[row][j]
    __shared__ __align__(16) float sWt[16 * 68];
    __shared__ float sB[16];
    __shared__ float sW2v[16];
    __shared__ float sB2;
    int tid = threadIdx.x;
    int fb = flags[0], fi = flags[1];
    for (int idx = tid; idx < 66 * 16; idx += blockDim.x) {
        int rrow = idx >> 4, jj = idx & 15;
        sWt[jj * 68 + rrow] = ldf(Wm1, fb, idx);
    }
    if (tid < 16) sB[tid] = ldf(bm1, fb, tid);
    else if (tid < 32) sW2v[tid - 16] = ldf(Wm2, fb, tid - 16);
    else if (tid == 32) sB2 = ldf(bm2, fb, 0);
    __syncthreads();

    int j = tid & 15;
    const float* wc = sWt + j * 68;
    float4 w0 = *(const float4*)(wc +  0), w1 = *(const float4*)(wc +  4);
    float4 w2 = *(const float4*)(wc +  8), w3 = *(const float4*)(wc + 12);
    float4 w4 = *(const float4*)(wc + 16), w5 = *(const float4*)(wc + 20);
    float4 w6 = *(const float4*)(wc + 24), w7 = *(const float4*)(wc + 28);
    float4 w8  = *(const float4*)(wc + 32), w9  = *(const float4*)(wc + 36);
    float4 w10 = *(const float4*)(wc + 40), w11 = *(const float4*)(wc + 44);
    float4 w12 = *(const float4*)(wc + 48), w13 = *(const float4*)(wc + 52);
    float4 w14 = *(const float4*)(wc + 56), w15 = *(const float4*)(wc + 60);
    float wea0 = wc[64], wea1 = wc[65];
    float bj = sB[j], w2j = sW2v[j], b2s = sB2;

    int gid = (blockIdx.x * blockDim.x + tid) >> 4;
    int ngroups = (gridDim.x * blockDim.x) >> 4;

    for (int e = gid; e < E; e += ngroups) {
        int r = ldi(ei, fi, e, n);
        int c = ldi(ei, fi, (size_t)E + e, n);
        float accj = bj;
        if (H2F) {
            float ac0 = 0.f, ac1 = 0.f;
            {
                const float4* hr = (const float4*)((const float*)h2 + r * 32);
                float4 a0 = hr[0], a1 = hr[1], a2 = hr[2], a3 = hr[3];
                float4 a4 = hr[4], a5 = hr[5], a6 = hr[6], a7 = hr[7];
                PK4(a0, w0) PK4(a1, w1) PK4(a2, w2) PK4(a3, w3)
                PK4(a4, w4) PK4(a5, w5) PK4(a6, w6) PK4(a7, w7)
            }
            {
                const float4* hc = (const float4*)((const float*)h2 + c * 32);
                float4 a0 = hc[0], a1 = hc[1], a2 = hc[2], a3 = hc[3];
                float4 a4 = hc[4], a5 = hc[5], a6 = hc[6], a7 = hc[7];
                PK4(a0, w8)  PK4(a1, w9)  PK4(a2, w10) PK4(a3, w11)
                PK4(a4, w12) PK4(a5, w13) PK4(a6, w14) PK4(a7, w15)
            }
            accj += ac0 + ac1;
        } else {
            const uint4* h2u4 = (const uint4*)h2;
            {
                const uint4* hr = h2u4 + (size_t)r * 4;
                uint4 a0 = hr[0], a1 = hr[1], a2 = hr[2], a3 = hr[3];
                ACC8(a0, w0, w1) ACC8(a1, w2, w3) ACC8(a2, w4, w5) ACC8(a3, w6, w7)
            }
            {
                const uint4* hc = h2u4 + (size_t)c * 4;
                uint4 a0 = hc[0], a1 = hc[1], a2 = hc[2], a3 = hc[3];
                ACC8(a0, w8, w9) ACC8(a1, w10, w11) ACC8(a2, w12, w13) ACC8(a3, w14, w15)
            }
        }
        accj += ldf(ea, fb, 2 * (size_t)e) * wea0 + ldf(ea, fb, 2 * (size_t)e + 1) * wea1;

        float pj = fmaxf(accj, 0.f) * w2j;
        pj += __shfl_xor(pj, 8, 16);
        pj += __shfl_xor(pj, 4, 16);
        pj += __shfl_xor(pj, 2, 16);
        pj += __shfl_xor(pj, 1, 16);
        if (j == 0) {
            float o = pj + b2s;
            if (fb) ((bf16*)out)[e] = __float2bfloat16(o);
            else    ((float*)out)[e] = o;
        }
    }
}
#undef ACC8
#undef PK4

extern "C" void kernel_launch(void* const* d_in, const int* in_sizes, int n_in,
                              void* d_out, int out_size, void* d_ws, size_t ws_size,
                              hipStream_t stream) {
    const void* x   = d_in[0];
    const int*  ei  = (const int*)d_in[1];
    const void* ea  = d_in[2];
    const void* W1  = d_in[3];
    const void* b1  = d_in[4];
    const void* W2  = d_in[5];
    const void* b2  = d_in[6];
    const void* Wm1 = d_in[7];
    const void* bm1 = d_in[8];
    const void* Wm2 = d_in[9];
    const void* bm2 = d_in[10];

    int n = in_sizes[0] / 2;   // x is [N,2]
    int E = in_sizes[2] / 2;   // edge_attr is [E,2]

    char* ws = (char*)d_ws;
    size_t off = 0;
    auto take = [&](size_t bytes) -> char* {
        char* p = ws + off;
        off += bytes;
        off = (off + 255) & ~(size_t)255;
        return p;
    };
    int* flags   = (int*)take(8);
    int* counts  = (int*)take((size_t)(n + 1) * 4);   // hist -> cursor
    float* dinv  = (float*)take((size_t)n * 4);
    int* rowptr  = (int*)take((size_t)(n + 1) * 4);
    int* chsum   = (int*)take(1024);
    int* srcs    = (int*)take((size_t)E * 4);
    unsigned short* xw2 = (unsigned short*)take((size_t)n * 32 * 2);
    // h2: prefer fp32 (halves edge_mlp VALU work) if workspace allows
    int h2f = (off + (size_t)n * 32 * 4 <= ws_size) ? 1 : 0;
    void* h2 = (void*)take((size_t)n * 32 * (h2f ? 4 : 2));

    if (off > ws_size) {
        int nf = out_size / 2;
        if (nf > 0) k_sentinel<<<(nf + 255) / 256, 256, 0, stream>>>((float*)d_out, nf);
        return;
    }

    const int B = 256;
    int nch = (n + 511) / 512;  // 196 <= 256
    k_detect<<<1, 64, 0, stream>>>(x, ei, flags);
    k_zero<<<(n + 1 + B - 1) / B, B, 0, stream>>>(counts, n + 1);
    k_hist<<<(E + B - 1) / B, B, 0, stream>>>(ei, flags, counts, E, n);
    k_scan1<<<nch, 512, 0, stream>>>(counts, rowptr, chsum, dinv, n);
    k_scan2<<<1, 256, 0, stream>>>(chsum, nch);
    k_scan3<<<nch, 512, 0, stream>>>(rowptr, chsum, counts, n, E);
    k_fill<<<(E + B - 1) / B, B, 0, stream>>>(ei, flags, counts, srcs, E, n);
    k_node1<<<((size_t)n * 32 + B - 1) / B, B, 0, stream>>>(x, flags, dinv, rowptr, srcs,
                                                            W1, b1, W2, xw2, n);
    if (h2f) {
        k_gather2<1><<<((size_t)n * 32 + B - 1) / B, B, 0, stream>>>(xw2, flags, dinv, rowptr,
                                                                     srcs, b2, h2, n);
        k_edge_mlp<1><<<2048, B, 0, stream>>>(ei, flags, h2, ea, Wm1, bm1, Wm2, bm2, d_out, E, n);
    } else {
        k_gather2<0><<<((size_t)n * 32 + B - 1) / B, B, 0, stream>>>(xw2, flags, dinv, rowptr,
                                                                     srcs, b2, h2, n);
        k_edge_mlp<0><<<2048, B, 0, stream>>>(ei, flags, h2, ea, Wm1, bm1, Wm2, bm2, d_out, E, n);
    }
}

// Round 9
// 471.772 us; speedup vs baseline: 1.9789x; 1.9789x over previous
//
#include <hip/hip_runtime.h>
#include <hip/hip_bf16.h>

typedef __hip_bfloat16 bf16;

// ---- adaptive loads: fb=1 -> bf16 data, fb=0 -> float32 data ----
__device__ __forceinline__ float ldf(const void* p, int fb, size_t i) {
    if (fb) {
        unsigned int u = ((const unsigned short*)p)[i];
        return __uint_as_float(u << 16);
    }
    return ((const float*)p)[i];
}
// fi=1 -> int64 underlying (read low word), fi=0 -> int32. Clamped to [0,n).
__device__ __forceinline__ int ldi(const int* p, int fi, size_t i, int n) {
    int v = fi ? p[2 * i] : p[i];
    return ((unsigned)v < (unsigned)n) ? v : 0;
}
__device__ __forceinline__ float bf2f_bits(unsigned short u) {
    return __uint_as_float(((unsigned int)u) << 16);
}
__device__ __forceinline__ float f16b2f(unsigned short u) {
    _Float16 h = __builtin_bit_cast(_Float16, u);
    return (float)h;
}
__device__ __forceinline__ unsigned short f2f16b(float f) {
    _Float16 h = (_Float16)f;
    return __builtin_bit_cast(unsigned short, h);
}

// ---------------- dtype detection ----------------
__global__ void k_detect(const void* x, const int* ei, int* flags) {
    if (threadIdx.x == 0 && blockIdx.x == 0) {
        const unsigned short* u = (const unsigned short*)x;
        int bad = 0;
        for (int i = 0; i < 128; ++i) {
            float v = bf2f_bits(u[i]);
            if (!(v > -64.f && v < 64.f)) bad++;  // NaN fails both
        }
        flags[0] = (bad >= 4) ? 0 : 1;  // 1 = floats are bf16
        int nz = 0;
        for (int i = 0; i < 64; ++i) nz |= ei[2 * i + 1];
        flags[1] = (nz == 0) ? 1 : 0;   // 1 = indices are int64
    }
}

__global__ void k_sentinel(float* out, int nfloats) {
    int i = blockIdx.x * blockDim.x + threadIdx.x;
    if (i < nfloats) out[i] = 1000.0f;
}

// ---------------- CSR build ----------------
__global__ void k_zero(int* counts, int n1) {
    int i = blockIdx.x * blockDim.x + threadIdx.x;
    if (i < n1) counts[i] = 0;
}

__global__ void k_hist(const int* __restrict__ ei, const int* __restrict__ flags,
                       int* counts, int E, int n) {
    int e = blockIdx.x * blockDim.x + threadIdx.x;
    if (e >= E) return;
    int c = ldi(ei, flags[1], (size_t)E + e, n);
    atomicAdd(&counts[c], 1);
}

// chunk = 512. scan1: per-chunk exclusive scan into rowptr; also dinv (fused).
__global__ void k_scan1(const int* __restrict__ counts, int* __restrict__ rowptr,
                        int* __restrict__ chsum, float* __restrict__ dinv, int n) {
    __shared__ int s[512];
    int t = threadIdx.x, i = blockIdx.x * 512 + t;
    int v = (i < n) ? counts[i] : 0;
    if (i < n) dinv[i] = rsqrtf((float)(v + 1));  // +1 self loop
    s[t] = v;
    __syncthreads();
    for (int off = 1; off < 512; off <<= 1) {
        int add = (t >= off) ? s[t - off] : 0;
        __syncthreads();
        s[t] += add;
        __syncthreads();
    }
    if (i < n) rowptr[i] = s[t] - v;            // chunk-local exclusive
    if (t == 511) chsum[blockIdx.x] = s[511];   // chunk total
}

// scan2: one block scans <=256 chunk sums (exclusive, in place)
__global__ void k_scan2(int* chsum, int nch) {
    __shared__ int s[256];
    int t = threadIdx.x;
    int v = (t < nch) ? chsum[t] : 0;
    s[t] = v;
    __syncthreads();
    for (int off = 1; off < 256; off <<= 1) {
        int add = (t >= off) ? s[t - off] : 0;
        __syncthreads();
        s[t] += add;
        __syncthreads();
    }
    if (t < nch) chsum[t] = s[t] - v;           // exclusive
}

// scan3: add chunk offsets; write cursor copy into counts; rowptr[n]=E
__global__ void k_scan3(int* __restrict__ rowptr, const int* __restrict__ chsum,
                        int* __restrict__ counts, int n, int E) {
    int t = threadIdx.x, i = blockIdx.x * 512 + t;
    if (i < n) {
        int val = rowptr[i] + chsum[blockIdx.x];
        rowptr[i] = val;
        counts[i] = val;  // cursor
    }
    if (blockIdx.x == 0 && t == 0) rowptr[n] = E;
}

__global__ void k_fill(const int* __restrict__ ei, const int* __restrict__ flags,
                       int* __restrict__ cursor, int* __restrict__ srcs, int E, int n) {
    int e = blockIdx.x * blockDim.x + threadIdx.x;
    if (e >= E) return;
    int fi = flags[1];
    int r = ldi(ei, fi, e, n);
    int c = ldi(ei, fi, (size_t)E + e, n);
    int pos = atomicAdd(&cursor[c], 1);
    srcs[pos] = r;
}

// ---------------- fused node stage 1: gather x + h1 MLP + xw2 ----------------
__global__ void k_node1(const void* __restrict__ x, const int* __restrict__ flags,
                        const float* __restrict__ dinv, const int* __restrict__ rowptr,
                        const int* __restrict__ srcs,
                        const void* __restrict__ W1, const void* __restrict__ b1,
                        const void* __restrict__ W2,
                        unsigned short* __restrict__ xw2, int n) {
    __shared__ float sW1[128];
    __shared__ float sb1[64];
    __shared__ float sW2[64 * 32];
    int tid = threadIdx.x;
    int fb = flags[0];
    for (int idx = tid; idx < 128; idx += blockDim.x) sW1[idx] = ldf(W1, fb, idx);
    for (int idx = tid; idx < 64; idx += blockDim.x)  sb1[idx] = ldf(b1, fb, idx);
    for (int idx = tid; idx < 64 * 32; idx += blockDim.x) sW2[idx] = ldf(W2, fb, idx);
    __syncthreads();
    int t = blockIdx.x * blockDim.x + tid;
    int i = t >> 5, lane = t & 31;
    if (i >= n) return;
    int start = rowptr[i], end = rowptr[i + 1];
    float di = dinv[i];
    float p0 = 0.f, p1 = 0.f;
    if (fb) {
        const unsigned int* xu = (const unsigned int*)x;  // one row = one dword
        for (int m = start + lane; m < end; m += 32) {
            int r = srcs[m];
            float dr = dinv[r];
            unsigned int w = xu[r];
            p0 = fmaf(dr, __uint_as_float(w << 16), p0);
            p1 = fmaf(dr, __uint_as_float(w & 0xffff0000u), p1);
        }
    } else {
        const float2* xf = (const float2*)x;
        for (int m = start + lane; m < end; m += 32) {
            int r = srcs[m];
            float dr = dinv[r];
            float2 xv = xf[r];
            p0 = fmaf(dr, xv.x, p0);
            p1 = fmaf(dr, xv.y, p1);
        }
    }
#pragma unroll
    for (int off = 16; off; off >>= 1) {
        p0 += __shfl_xor(p0, off, 32);
        p1 += __shfl_xor(p1, off, 32);
    }
    float xi0, xi1;
    if (fb) {
        unsigned int w = ((const unsigned int*)x)[i];
        xi0 = __uint_as_float(w << 16);
        xi1 = __uint_as_float(w & 0xffff0000u);
    } else {
        float2 xv = ((const float2*)x)[i];
        xi0 = xv.x; xi1 = xv.y;
    }
    float a0 = di * fmaf(di, xi0, p0);
    float a1 = di * fmaf(di, xi1, p1);
    int j = lane;
    float s = 0.f;
#pragma unroll 4
    for (int k = 0; k < 64; ++k) {
        float h = fmaxf(fmaf(a0, sW1[k], fmaf(a1, sW1[64 + k], sb1[k])), 0.f);
        s = fmaf(h, sW2[k * 32 + j], s);
    }
    xw2[t] = (unsigned short)(__float_as_uint(s) >> 16);
}

// ---------------- layer-2 gather + edge-MLP first-layer hoist ----------------
// Computes h2[i] in registers (lane k of 32), then directly emits
//   q1[i][j] = bm1[j] + sum_k h2[k]*Wm1[k][j]       (lanes 0..15)
//   q2[i][j] =          sum_k h2[k]*Wm1[32+k][j]    (lanes 16..31)
// stored fp16 (3.2 MB each -> L2-resident; fp16 mantissa keeps rounding ~5e-4).
__global__ void k_gather2q(const unsigned short* __restrict__ xw2, const int* __restrict__ flags,
                           const float* __restrict__ dinv, const int* __restrict__ rowptr,
                           const int* __restrict__ srcs, const void* __restrict__ b2v,
                           const void* __restrict__ Wm1, const void* __restrict__ bm1,
                           unsigned short* __restrict__ q1, unsigned short* __restrict__ q2, int n) {
    __shared__ float sW[64 * 16];   // Wm1 rows 0..63, row-major [row][j]
    __shared__ float sb1[16];
    __shared__ float sb2[32];
    int tid = threadIdx.x;
    int fb = flags[0];
    for (int idx = tid; idx < 64 * 16; idx += blockDim.x) sW[idx] = ldf(Wm1, fb, idx);
    if (tid < 16) sb1[tid] = ldf(bm1, fb, tid);
    if (tid >= 16 && tid < 48) sb2[tid - 16] = ldf(b2v, fb, tid - 16);
    __syncthreads();
    int t = blockIdx.x * blockDim.x + tid;
    int i = t >> 5, lane = t & 31;
    if (i >= n) return;
    float di = dinv[i];
    float acc = di * bf2f_bits(xw2[i * 32 + lane]);
    int mend = rowptr[i + 1];
    for (int m = rowptr[i]; m < mend; ++m) {
        int r = srcs[m];
        acc = fmaf(dinv[r], bf2f_bits(xw2[r * 32 + lane]), acc);
    }
    float v = fmaxf(fmaf(di, acc, sb2[lane]), 0.f);   // h2[i][lane]

    int j = lane & 15;
    int half = lane >> 4;
    float q = half ? 0.f : sb1[j];
    const float* wbase = sW + half * (32 * 16);
#pragma unroll 8
    for (int k = 0; k < 32; ++k) {
        float h = __shfl(v, k, 32);
        q = fmaf(h, wbase[k * 16 + j], q);
    }
    unsigned short qb = f2f16b(q);
    if (half == 0) q1[i * 16 + j] = qb;
    else           q2[i * 16 + j] = qb;
}

// ---------------- edge MLP: 1 thread/edge on fp16 q-tables ----------------
// per edge: hmid[j] = relu(q1[r][j] + q2[c][j] + ea0*Wm1[64][j] + ea1*Wm1[65][j]);
//           out    = bm2 + sum_j hmid[j]*Wm2[j]
__global__ void k_edge_mlp2(const int* __restrict__ ei, const int* __restrict__ flags,
                            const unsigned short* __restrict__ q1,
                            const unsigned short* __restrict__ q2,
                            const void* __restrict__ ea,
                            const void* __restrict__ Wm1, const void* __restrict__ Wm2,
                            const void* __restrict__ bm2,
                            void* __restrict__ out, int E, int n) {
    __shared__ __align__(16) float sWa[16];   // Wm1 row 64
    __shared__ __align__(16) float sWb[16];   // Wm1 row 65
    __shared__ __align__(16) float sW2[16];
    __shared__ float sB2;
    int tid = threadIdx.x;
    int fb = flags[0], fi = flags[1];
    if (tid < 16) sWa[tid] = ldf(Wm1, fb, 64 * 16 + tid);
    else if (tid < 32) sWb[tid - 16] = ldf(Wm1, fb, 65 * 16 + (tid - 16));
    else if (tid < 48) sW2[tid - 32] = ldf(Wm2, fb, tid - 32);
    else if (tid == 48) sB2 = ldf(bm2, fb, 0);
    __syncthreads();

    int e = blockIdx.x * blockDim.x + tid;
    if (e >= E) return;
    int r = ldi(ei, fi, e, n);
    int c = ldi(ei, fi, (size_t)E + e, n);
    float ea0 = ldf(ea, fb, 2 * (size_t)e), ea1 = ldf(ea, fb, 2 * (size_t)e + 1);

    const uint4* q1u = (const uint4*)q1;
    const uint4* q2u = (const uint4*)q2;
    uint4 A0 = q1u[r * 2], A1 = q1u[r * 2 + 1];
    uint4 B0 = q2u[c * 2], B1 = q2u[c * 2 + 1];

    float o = sB2;
#define E2(uA, uB, JA, JB)                                                          \
    {                                                                               \
        float h0 = f16b2f((unsigned short)((uA) & 0xffffu))                         \
                 + f16b2f((unsigned short)((uB) & 0xffffu))                         \
                 + ea0 * sWa[JA] + ea1 * sWb[JA];                                   \
        o = fmaf(fmaxf(h0, 0.f), sW2[JA], o);                                       \
        float h1 = f16b2f((unsigned short)((uA) >> 16))                             \
                 + f16b2f((unsigned short)((uB) >> 16))                             \
                 + ea0 * sWa[JB] + ea1 * sWb[JB];                                   \
        o = fmaf(fmaxf(h1, 0.f), sW2[JB], o);                                       \
    }
    E2(A0.x, B0.x, 0, 1)   E2(A0.y, B0.y, 2, 3)
    E2(A0.z, B0.z, 4, 5)   E2(A0.w, B0.w, 6, 7)
    E2(A1.x, B1.x, 8, 9)   E2(A1.y, B1.y, 10, 11)
    E2(A1.z, B1.z, 12, 13) E2(A1.w, B1.w, 14, 15)
#undef E2

    if (fb) ((bf16*)out)[e] = __float2bfloat16(o);
    else    ((float*)out)[e] = o;
}

extern "C" void kernel_launch(void* const* d_in, const int* in_sizes, int n_in,
                              void* d_out, int out_size, void* d_ws, size_t ws_size,
                              hipStream_t stream) {
    const void* x   = d_in[0];
    const int*  ei  = (const int*)d_in[1];
    const void* ea  = d_in[2];
    const void* W1  = d_in[3];
    const void* b1  = d_in[4];
    const void* W2  = d_in[5];
    const void* b2  = d_in[6];
    const void* Wm1 = d_in[7];
    const void* bm1 = d_in[8];
    const void* Wm2 = d_in[9];
    const void* bm2 = d_in[10];

    int n = in_sizes[0] / 2;   // x is [N,2]
    int E = in_sizes[2] / 2;   // edge_attr is [E,2]

    char* ws = (char*)d_ws;
    size_t off = 0;
    auto take = [&](size_t bytes) -> char* {
        char* p = ws + off;
        off += bytes;
        off = (off + 255) & ~(size_t)255;
        return p;
    };
    int* flags   = (int*)take(8);
    int* counts  = (int*)take((size_t)(n + 1) * 4);   // hist -> cursor
    float* dinv  = (float*)take((size_t)n * 4);
    int* rowptr  = (int*)take((size_t)(n + 1) * 4);
    int* chsum   = (int*)take(1024);
    int* srcs    = (int*)take((size_t)E * 4);
    unsigned short* xw2 = (unsigned short*)take((size_t)n * 32 * 2);
    unsigned short* q1  = (unsigned short*)take((size_t)n * 16 * 2);
    unsigned short* q2  = (unsigned short*)take((size_t)n * 16 * 2);

    if (off > ws_size) {
        int nf = out_size / 2;
        if (nf > 0) k_sentinel<<<(nf + 255) / 256, 256, 0, stream>>>((float*)d_out, nf);
        return;
    }

    const int B = 256;
    int nch = (n + 511) / 512;  // 196 <= 256
    k_detect<<<1, 64, 0, stream>>>(x, ei, flags);
    k_zero<<<(n + 1 + B - 1) / B, B, 0, stream>>>(counts, n + 1);
    k_hist<<<(E + B - 1) / B, B, 0, stream>>>(ei, flags, counts, E, n);
    k_scan1<<<nch, 512, 0, stream>>>(counts, rowptr, chsum, dinv, n);
    k_scan2<<<1, 256, 0, stream>>>(chsum, nch);
    k_scan3<<<nch, 512, 0, stream>>>(rowptr, chsum, counts, n, E);
    k_fill<<<(E + B - 1) / B, B, 0, stream>>>(ei, flags, counts, srcs, E, n);
    k_node1<<<((size_t)n * 32 + B - 1) / B, B, 0, stream>>>(x, flags, dinv, rowptr, srcs,
                                                            W1, b1, W2, xw2, n);
    k_gather2q<<<((size_t)n * 32 + B - 1) / B, B, 0, stream>>>(xw2, flags, dinv, rowptr, srcs,
                                                               b2, Wm1, bm1, q1, q2, n);
    k_edge_mlp2<<<(E + B - 1) / B, B, 0, stream>>>(ei, flags, q1, q2, ea, Wm1, Wm2, bm2,
                                                   d_out, E, n);
}

// Round 10
// 405.223 us; speedup vs baseline: 2.3039x; 1.1642x over previous
//
#include <hip/hip_runtime.h>
#include <hip/hip_bf16.h>

typedef __hip_bfloat16 bf16;

// ---- adaptive loads: fb=1 -> bf16 data, fb=0 -> float32 data ----
__device__ __forceinline__ float ldf(const void* p, int fb, size_t i) {
    if (fb) {
        unsigned int u = ((const unsigned short*)p)[i];
        return __uint_as_float(u << 16);
    }
    return ((const float*)p)[i];
}
// fi=1 -> int64 underlying (read low word), fi=0 -> int32. Clamped to [0,n).
__device__ __forceinline__ int ldi(const int* p, int fi, size_t i, int n) {
    int v = fi ? p[2 * i] : p[i];
    return ((unsigned)v < (unsigned)n) ? v : 0;
}
__device__ __forceinline__ float bf2f_bits(unsigned short u) {
    return __uint_as_float(((unsigned int)u) << 16);
}
__device__ __forceinline__ float f16b2f(unsigned short u) {
    _Float16 h = __builtin_bit_cast(_Float16, u);
    return (float)h;
}
__device__ __forceinline__ unsigned short f2f16b(float f) {
    _Float16 h = (_Float16)f;
    return __builtin_bit_cast(unsigned short, h);
}

// ---------------- dtype detection (parallel: 64 lanes, ~2 dependent loads) ----------------
__global__ void k_detect(const void* x, const int* ei, int* flags) {
    int lane = threadIdx.x;  // 64 threads, 1 wave
    const unsigned short* u = (const unsigned short*)x;
    float v0 = bf2f_bits(u[2 * lane]);
    float v1 = bf2f_bits(u[2 * lane + 1]);
    unsigned long long m0 = __ballot(!(v0 > -64.f && v0 < 64.f));
    unsigned long long m1 = __ballot(!(v1 > -64.f && v1 < 64.f));
    unsigned long long mz = __ballot(ei[2 * lane + 1] != 0);
    if (lane == 0) {
        int bad = __popcll(m0) + __popcll(m1);
        flags[0] = (bad >= 4) ? 0 : 1;  // 1 = floats are bf16
        flags[1] = (mz == 0) ? 1 : 0;   // 1 = indices are int64
    }
}

__global__ void k_sentinel(float* out, int nfloats) {
    int i = blockIdx.x * blockDim.x + threadIdx.x;
    if (i < nfloats) out[i] = 1000.0f;
}

// ---------------- CSR build ----------------
__global__ void k_zero(int* counts, int n1) {
    int i = blockIdx.x * blockDim.x + threadIdx.x;
    if (i < n1) counts[i] = 0;
}

// 4 edges/thread: 4 independent atomic chains (MLP for the latency-bound scatter)
__global__ void k_hist(const int* __restrict__ ei, const int* __restrict__ flags,
                       int* counts, int E, int n) {
    int t = blockIdx.x * blockDim.x + threadIdx.x;
    int e0 = t * 4;
    if (e0 >= E) return;
    int fi = flags[1];
    if (e0 + 4 <= E) {
        int c0 = ldi(ei, fi, (size_t)E + e0, n);
        int c1 = ldi(ei, fi, (size_t)E + e0 + 1, n);
        int c2 = ldi(ei, fi, (size_t)E + e0 + 2, n);
        int c3 = ldi(ei, fi, (size_t)E + e0 + 3, n);
        atomicAdd(&counts[c0], 1);
        atomicAdd(&counts[c1], 1);
        atomicAdd(&counts[c2], 1);
        atomicAdd(&counts[c3], 1);
    } else {
        for (int e = e0; e < E; ++e)
            atomicAdd(&counts[ldi(ei, fi, (size_t)E + e, n)], 1);
    }
}

// chunk = 512. scan1: per-chunk exclusive scan into rowptr; fused dinv + xd=dinv*x.
__global__ void k_scan1(const int* __restrict__ counts, int* __restrict__ rowptr,
                        int* __restrict__ chsum, float* __restrict__ dinv,
                        const void* __restrict__ x, const int* __restrict__ flags,
                        float2* __restrict__ xd, int n) {
    __shared__ int s[512];
    int t = threadIdx.x, i = blockIdx.x * 512 + t;
    int v = (i < n) ? counts[i] : 0;
    if (i < n) {
        float di = rsqrtf((float)(v + 1));  // +1 self loop
        dinv[i] = di;
        int fb = flags[0];
        float2 o;
        o.x = di * ldf(x, fb, 2 * (size_t)i);
        o.y = di * ldf(x, fb, 2 * (size_t)i + 1);
        xd[i] = o;
    }
    s[t] = v;
    __syncthreads();
    for (int off = 1; off < 512; off <<= 1) {
        int add = (t >= off) ? s[t - off] : 0;
        __syncthreads();
        s[t] += add;
        __syncthreads();
    }
    if (i < n) rowptr[i] = s[t] - v;            // chunk-local exclusive
    if (t == 511) chsum[blockIdx.x] = s[511];   // chunk total
}

// scan2: one block scans <=256 chunk sums (exclusive, in place)
__global__ void k_scan2(int* chsum, int nch) {
    __shared__ int s[256];
    int t = threadIdx.x;
    int v = (t < nch) ? chsum[t] : 0;
    s[t] = v;
    __syncthreads();
    for (int off = 1; off < 256; off <<= 1) {
        int add = (t >= off) ? s[t - off] : 0;
        __syncthreads();
        s[t] += add;
        __syncthreads();
    }
    if (t < nch) chsum[t] = s[t] - v;           // exclusive
}

// scan3: add chunk offsets; write cursor copy into counts; rowptr[n]=E
__global__ void k_scan3(int* __restrict__ rowptr, const int* __restrict__ chsum,
                        int* __restrict__ counts, int n, int E) {
    int t = threadIdx.x, i = blockIdx.x * 512 + t;
    if (i < n) {
        int val = rowptr[i] + chsum[blockIdx.x];
        rowptr[i] = val;
        counts[i] = val;  // cursor
    }
    if (blockIdx.x == 0 && t == 0) rowptr[n] = E;
}

// 4 edges/thread: independent atomic->store chains
__global__ void k_fill(const int* __restrict__ ei, const int* __restrict__ flags,
                       int* __restrict__ cursor, int* __restrict__ srcs, int E, int n) {
    int t = blockIdx.x * blockDim.x + threadIdx.x;
    int e0 = t * 4;
    if (e0 >= E) return;
    int fi = flags[1];
    if (e0 + 4 <= E) {
        int r0 = ldi(ei, fi, e0, n),     c0 = ldi(ei, fi, (size_t)E + e0, n);
        int r1 = ldi(ei, fi, e0 + 1, n), c1 = ldi(ei, fi, (size_t)E + e0 + 1, n);
        int r2 = ldi(ei, fi, e0 + 2, n), c2 = ldi(ei, fi, (size_t)E + e0 + 2, n);
        int r3 = ldi(ei, fi, e0 + 3, n), c3 = ldi(ei, fi, (size_t)E + e0 + 3, n);
        int p0 = atomicAdd(&cursor[c0], 1);
        int p1 = atomicAdd(&cursor[c1], 1);
        int p2 = atomicAdd(&cursor[c2], 1);
        int p3 = atomicAdd(&cursor[c3], 1);
        srcs[p0] = r0;
        srcs[p1] = r1;
        srcs[p2] = r2;
        srcs[p3] = r3;
    } else {
        for (int e = e0; e < E; ++e) {
            int r = ldi(ei, fi, e, n);
            int c = ldi(ei, fi, (size_t)E + e, n);
            srcs[atomicAdd(&cursor[c], 1)] = r;
        }
    }
}

// ---------------- fused node stage 1: gather xd + h1 MLP + y = dinv*xw2 ----------------
__global__ void k_node1(const float2* __restrict__ xd, const int* __restrict__ flags,
                        const float* __restrict__ dinv, const int* __restrict__ rowptr,
                        const int* __restrict__ srcs,
                        const void* __restrict__ W1, const void* __restrict__ b1,
                        const void* __restrict__ W2,
                        unsigned short* __restrict__ y, int n) {
    __shared__ float sW1[128];
    __shared__ float sb1[64];
    __shared__ float sW2[64 * 32];
    int tid = threadIdx.x;
    int fb = flags[0];
    for (int idx = tid; idx < 128; idx += blockDim.x) sW1[idx] = ldf(W1, fb, idx);
    for (int idx = tid; idx < 64; idx += blockDim.x)  sb1[idx] = ldf(b1, fb, idx);
    for (int idx = tid; idx < 64 * 32; idx += blockDim.x) sW2[idx] = ldf(W2, fb, idx);
    __syncthreads();
    int t = blockIdx.x * blockDim.x + tid;
    int i = t >> 5, lane = t & 31;
    if (i >= n) return;
    int start = rowptr[i], end = rowptr[i + 1];
    float di = dinv[i];
    float p0 = 0.f, p1 = 0.f;
    for (int m = start + lane; m < end; m += 32) {
        int r = srcs[m];
        float2 xv = xd[r];   // already dinv[r]*x[r]
        p0 += xv.x;
        p1 += xv.y;
    }
#pragma unroll
    for (int off = 16; off; off >>= 1) {
        p0 += __shfl_xor(p0, off, 32);
        p1 += __shfl_xor(p1, off, 32);
    }
    float2 xi = xd[i];       // dinv[i]*x[i] == self-loop term pre-factor
    float a0 = di * (p0 + xi.x);
    float a1 = di * (p1 + xi.y);
    int j = lane;
    float s = 0.f;
#pragma unroll 4
    for (int k = 0; k < 64; ++k) {
        float h = fmaxf(fmaf(a0, sW1[k], fmaf(a1, sW1[64 + k], sb1[k])), 0.f);
        s = fmaf(h, sW2[k * 32 + j], s);
    }
    float ys = di * s;  // premultiplied: gather-2 becomes pure adds
    y[t] = (unsigned short)(__float_as_uint(ys) >> 16);
}

// ---------------- layer-2 gather (pure adds on y) + edge-MLP first-layer hoist ----------------
__global__ void k_gather2q(const unsigned short* __restrict__ y, const int* __restrict__ flags,
                           const float* __restrict__ dinv, const int* __restrict__ rowptr,
                           const int* __restrict__ srcs, const void* __restrict__ b2v,
                           const void* __restrict__ Wm1, const void* __restrict__ bm1,
                           unsigned short* __restrict__ q1, unsigned short* __restrict__ q2, int n) {
    __shared__ float sW[64 * 16];   // Wm1 rows 0..63, row-major [row][j]
    __shared__ float sb1[16];
    __shared__ float sb2[32];
    int tid = threadIdx.x;
    int fb = flags[0];
    for (int idx = tid; idx < 64 * 16; idx += blockDim.x) sW[idx] = ldf(Wm1, fb, idx);
    if (tid < 16) sb1[tid] = ldf(bm1, fb, tid);
    if (tid >= 16 && tid < 48) sb2[tid - 16] = ldf(b2v, fb, tid - 16);
    __syncthreads();
    int t = blockIdx.x * blockDim.x + tid;
    int i = t >> 5, lane = t & 31;
    if (i >= n) return;
    float di = dinv[i];
    int start = rowptr[i], end = rowptr[i + 1];
    float acc = bf2f_bits(y[i * 32 + lane]);  // self term
    for (int base = start; base < end; base += 32) {
        int cnt = end - base; if (cnt > 32) cnt = 32;
        int sl = (lane < cnt) ? srcs[base + lane] : 0;  // one coalesced load / 32 nbrs
        int k = 0;
        for (; k + 4 <= cnt; k += 4) {
            int ra = __shfl(sl, k, 32),     rb = __shfl(sl, k + 1, 32);
            int rc = __shfl(sl, k + 2, 32), rd = __shfl(sl, k + 3, 32);
            float wa = bf2f_bits(y[ra * 32 + lane]);
            float wb = bf2f_bits(y[rb * 32 + lane]);
            float wc = bf2f_bits(y[rc * 32 + lane]);
            float wd = bf2f_bits(y[rd * 32 + lane]);
            acc += (wa + wb) + (wc + wd);
        }
        for (; k < cnt; ++k) {
            int rr = __shfl(sl, k, 32);
            acc += bf2f_bits(y[rr * 32 + lane]);
        }
    }
    float v = fmaxf(fmaf(di, acc, sb2[lane]), 0.f);   // h2[i][lane]

    int j = lane & 15;
    int half = lane >> 4;
    float q = half ? 0.f : sb1[j];
    const float* wbase = sW + half * (32 * 16);
#pragma unroll 8
    for (int k = 0; k < 32; ++k) {
        float h = __shfl(v, k, 32);
        q = fmaf(h, wbase[k * 16 + j], q);
    }
    unsigned short qb = f2f16b(q);
    if (half == 0) q1[i * 16 + j] = qb;
    else           q2[i * 16 + j] = qb;
}

// ---------------- edge MLP: 1 thread/edge on fp16 q-tables ----------------
__global__ void k_edge_mlp2(const int* __restrict__ ei, const int* __restrict__ flags,
                            const unsigned short* __restrict__ q1,
                            const unsigned short* __restrict__ q2,
                            const void* __restrict__ ea,
                            const void* __restrict__ Wm1, const void* __restrict__ Wm2,
                            const void* __restrict__ bm2,
                            void* __restrict__ out, int E, int n) {
    __shared__ __align__(16) float sWa[16];   // Wm1 row 64
    __shared__ __align__(16) float sWb[16];   // Wm1 row 65
    __shared__ __align__(16) float sW2[16];
    __shared__ float sB2;
    int tid = threadIdx.x;
    int fb = flags[0], fi = flags[1];
    if (tid < 16) sWa[tid] = ldf(Wm1, fb, 64 * 16 + tid);
    else if (tid < 32) sWb[tid - 16] = ldf(Wm1, fb, 65 * 16 + (tid - 16));
    else if (tid < 48) sW2[tid - 32] = ldf(Wm2, fb, tid - 32);
    else if (tid == 48) sB2 = ldf(bm2, fb, 0);
    __syncthreads();

    int e = blockIdx.x * blockDim.x + tid;
    if (e >= E) return;
    int r = ldi(ei, fi, e, n);
    int c = ldi(ei, fi, (size_t)E + e, n);
    float ea0 = ldf(ea, fb, 2 * (size_t)e), ea1 = ldf(ea, fb, 2 * (size_t)e + 1);

    const uint4* q1u = (const uint4*)q1;
    const uint4* q2u = (const uint4*)q2;
    uint4 A0 = q1u[r * 2], A1 = q1u[r * 2 + 1];
    uint4 B0 = q2u[c * 2], B1 = q2u[c * 2 + 1];

    float o = sB2;
#define E2(uA, uB, JA, JB)                                                          \
    {                                                                               \
        float h0 = f16b2f((unsigned short)((uA) & 0xffffu))                         \
                 + f16b2f((unsigned short)((uB) & 0xffffu))                         \
                 + ea0 * sWa[JA] + ea1 * sWb[JA];                                   \
        o = fmaf(fmaxf(h0, 0.f), sW2[JA], o);                                       \
        float h1 = f16b2f((unsigned short)((uA) >> 16))                             \
                 + f16b2f((unsigned short)((uB) >> 16))                             \
                 + ea0 * sWa[JB] + ea1 * sWb[JB];                                   \
        o = fmaf(fmaxf(h1, 0.f), sW2[JB], o);                                       \
    }
    E2(A0.x, B0.x, 0, 1)   E2(A0.y, B0.y, 2, 3)
    E2(A0.z, B0.z, 4, 5)   E2(A0.w, B0.w, 6, 7)
    E2(A1.x, B1.x, 8, 9)   E2(A1.y, B1.y, 10, 11)
    E2(A1.z, B1.z, 12, 13) E2(A1.w, B1.w, 14, 15)
#undef E2

    if (fb) ((bf16*)out)[e] = __float2bfloat16(o);
    else    ((float*)out)[e] = o;
}

extern "C" void kernel_launch(void* const* d_in, const int* in_sizes, int n_in,
                              void* d_out, int out_size, void* d_ws, size_t ws_size,
                              hipStream_t stream) {
    const void* x   = d_in[0];
    const int*  ei  = (const int*)d_in[1];
    const void* ea  = d_in[2];
    const void* W1  = d_in[3];
    const void* b1  = d_in[4];
    const void* W2  = d_in[5];
    const void* b2  = d_in[6];
    const void* Wm1 = d_in[7];
    const void* bm1 = d_in[8];
    const void* Wm2 = d_in[9];
    const void* bm2 = d_in[10];

    int n = in_sizes[0] / 2;   // x is [N,2]
    int E = in_sizes[2] / 2;   // edge_attr is [E,2]

    char* ws = (char*)d_ws;
    size_t off = 0;
    auto take = [&](size_t bytes) -> char* {
        char* p = ws + off;
        off += bytes;
        off = (off + 255) & ~(size_t)255;
        return p;
    };
    int* flags   = (int*)take(8);
    int* counts  = (int*)take((size_t)(n + 1) * 4);   // hist -> cursor
    float* dinv  = (float*)take((size_t)n * 4);
    float2* xd   = (float2*)take((size_t)n * 8);
    int* rowptr  = (int*)take((size_t)(n + 1) * 4);
    int* chsum   = (int*)take(1024);
    int* srcs    = (int*)take((size_t)E * 4);
    unsigned short* y   = (unsigned short*)take((size_t)n * 32 * 2);
    unsigned short* q1  = (unsigned short*)take((size_t)n * 16 * 2);
    unsigned short* q2  = (unsigned short*)take((size_t)n * 16 * 2);

    if (off > ws_size) {
        int nf = out_size / 2;
        if (nf > 0) k_sentinel<<<(nf + 255) / 256, 256, 0, stream>>>((float*)d_out, nf);
        return;
    }

    const int B = 256;
    int nch = (n + 511) / 512;  // 196 <= 256
    int E4 = (E + 3) / 4;
    k_detect<<<1, 64, 0, stream>>>(x, ei, flags);
    k_zero<<<(n + 1 + B - 1) / B, B, 0, stream>>>(counts, n + 1);
    k_hist<<<(E4 + B - 1) / B, B, 0, stream>>>(ei, flags, counts, E, n);
    k_scan1<<<nch, 512, 0, stream>>>(counts, rowptr, chsum, dinv, x, flags, xd, n);
    k_scan2<<<1, 256, 0, stream>>>(chsum, nch);
    k_scan3<<<nch, 512, 0, stream>>>(rowptr, chsum, counts, n, E);
    k_fill<<<(E4 + B - 1) / B, B, 0, stream>>>(ei, flags, counts, srcs, E, n);
    k_node1<<<((size_t)n * 32 + B - 1) / B, B, 0, stream>>>(xd, flags, dinv, rowptr, srcs,
                                                            W1, b1, W2, y, n);
    k_gather2q<<<((size_t)n * 32 + B - 1) / B, B, 0, stream>>>(y, flags, dinv, rowptr, srcs,
                                                               b2, Wm1, bm1, q1, q2, n);
    k_edge_mlp2<<<(E + B - 1) / B, B, 0, stream>>>(ei, flags, q1, q2, ea, Wm1, Wm2, bm2,
                                                   d_out, E, n);
}

// Round 11
// 324.621 us; speedup vs baseline: 2.8760x; 1.2483x over previous
//
#include <hip/hip_runtime.h>
#include <hip/hip_bf16.h>

typedef __hip_bfloat16 bf16;

// ---- adaptive loads: fb=1 -> bf16 data, fb=0 -> float32 data ----
__device__ __forceinline__ float ldf(const void* p, int fb, size_t i) {
    if (fb) {
        unsigned int u = ((const unsigned short*)p)[i];
        return __uint_as_float(u << 16);
    }
    return ((const float*)p)[i];
}
// fi=1 -> int64 underlying (read low word), fi=0 -> int32. Clamped to [0,n).
__device__ __forceinline__ int ldi(const int* p, int fi, size_t i, int n) {
    int v = fi ? p[2 * i] : p[i];
    return ((unsigned)v < (unsigned)n) ? v : 0;
}
__device__ __forceinline__ float bf2f_bits(unsigned short u) {
    return __uint_as_float(((unsigned int)u) << 16);
}
__device__ __forceinline__ float f16b2f(unsigned short u) {
    _Float16 h = __builtin_bit_cast(_Float16, u);
    return (float)h;
}
__device__ __forceinline__ unsigned short f2f16b(float f) {
    _Float16 h = (_Float16)f;
    return __builtin_bit_cast(unsigned short, h);
}

// ---------------- dtype detection (parallel: 64 lanes) ----------------
__global__ void k_detect(const void* x, const int* ei, int* flags) {
    int lane = threadIdx.x;  // 64 threads, 1 wave
    const unsigned short* u = (const unsigned short*)x;
    float v0 = bf2f_bits(u[2 * lane]);
    float v1 = bf2f_bits(u[2 * lane + 1]);
    unsigned long long m0 = __ballot(!(v0 > -64.f && v0 < 64.f));
    unsigned long long m1 = __ballot(!(v1 > -64.f && v1 < 64.f));
    unsigned long long mz = __ballot(ei[2 * lane + 1] != 0);
    if (lane == 0) {
        int bad = __popcll(m0) + __popcll(m1);
        flags[0] = (bad >= 4) ? 0 : 1;  // 1 = floats are bf16
        flags[1] = (mz == 0) ? 1 : 0;   // 1 = indices are int64
    }
}

__global__ void k_sentinel(float* out, int nfloats) {
    int i = blockIdx.x * blockDim.x + threadIdx.x;
    if (i < nfloats) out[i] = 1000.0f;
}

// ---------------- CSR build ----------------
__global__ void k_zero(int* counts, int n1) {
    int i = blockIdx.x * blockDim.x + threadIdx.x;
    if (i < n1) counts[i] = 0;
}

// 4 edges/thread; atomic return value IS the edge's rank within its c-group —
// persist it so k_fill needs no atomic at all.
__global__ void k_hist(const int* __restrict__ ei, const int* __restrict__ flags,
                       int* counts, int* __restrict__ rank, int E, int n) {
    int t = blockIdx.x * blockDim.x + threadIdx.x;
    int e0 = t * 4;
    if (e0 >= E) return;
    int fi = flags[1];
    if (e0 + 4 <= E) {
        int c0 = ldi(ei, fi, (size_t)E + e0, n);
        int c1 = ldi(ei, fi, (size_t)E + e0 + 1, n);
        int c2 = ldi(ei, fi, (size_t)E + e0 + 2, n);
        int c3 = ldi(ei, fi, (size_t)E + e0 + 3, n);
        int k0 = atomicAdd(&counts[c0], 1);
        int k1 = atomicAdd(&counts[c1], 1);
        int k2 = atomicAdd(&counts[c2], 1);
        int k3 = atomicAdd(&counts[c3], 1);
        rank[e0]     = k0;
        rank[e0 + 1] = k1;
        rank[e0 + 2] = k2;
        rank[e0 + 3] = k3;
    } else {
        for (int e = e0; e < E; ++e)
            rank[e] = atomicAdd(&counts[ldi(ei, fi, (size_t)E + e, n)], 1);
    }
}

// chunk = 512. scan1: per-chunk exclusive scan into rowptr; fused dinv + xd=dinv*x.
__global__ void k_scan1(const int* __restrict__ counts, int* __restrict__ rowptr,
                        int* __restrict__ chsum, float* __restrict__ dinv,
                        const void* __restrict__ x, const int* __restrict__ flags,
                        float2* __restrict__ xd, int n) {
    __shared__ int s[512];
    int t = threadIdx.x, i = blockIdx.x * 512 + t;
    int v = (i < n) ? counts[i] : 0;
    if (i < n) {
        float di = rsqrtf((float)(v + 1));  // +1 self loop
        dinv[i] = di;
        int fb = flags[0];
        float2 o;
        o.x = di * ldf(x, fb, 2 * (size_t)i);
        o.y = di * ldf(x, fb, 2 * (size_t)i + 1);
        xd[i] = o;
    }
    s[t] = v;
    __syncthreads();
    for (int off = 1; off < 512; off <<= 1) {
        int add = (t >= off) ? s[t - off] : 0;
        __syncthreads();
        s[t] += add;
        __syncthreads();
    }
    if (i < n) rowptr[i] = s[t] - v;            // chunk-local exclusive
    if (t == 511) chsum[blockIdx.x] = s[511];   // chunk total
}

// scan2: one block scans <=256 chunk sums (exclusive, in place)
__global__ void k_scan2(int* chsum, int nch) {
    __shared__ int s[256];
    int t = threadIdx.x;
    int v = (t < nch) ? chsum[t] : 0;
    s[t] = v;
    __syncthreads();
    for (int off = 1; off < 256; off <<= 1) {
        int add = (t >= off) ? s[t - off] : 0;
        __syncthreads();
        s[t] += add;
        __syncthreads();
    }
    if (t < nch) chsum[t] = s[t] - v;           // exclusive
}

// scan3: add chunk offsets; rowptr[n]=E
__global__ void k_scan3(int* __restrict__ rowptr, const int* __restrict__ chsum,
                        int n, int E) {
    int t = threadIdx.x, i = blockIdx.x * 512 + t;
    if (i < n) rowptr[i] += chsum[blockIdx.x];
    if (blockIdx.x == 0 && t == 0) rowptr[n] = E;
}

// atomic-free fill: pos = rowptr[c] + rank[e]; 4 independent chains/thread.
__global__ void k_fill(const int* __restrict__ ei, const int* __restrict__ flags,
                       const int* __restrict__ rowptr, const int* __restrict__ rank,
                       int* __restrict__ srcs, int E, int n) {
    int t = blockIdx.x * blockDim.x + threadIdx.x;
    int e0 = t * 4;
    if (e0 >= E) return;
    int fi = flags[1];
    if (e0 + 4 <= E) {
        int r0 = ldi(ei, fi, e0, n),     c0 = ldi(ei, fi, (size_t)E + e0, n);
        int r1 = ldi(ei, fi, e0 + 1, n), c1 = ldi(ei, fi, (size_t)E + e0 + 1, n);
        int r2 = ldi(ei, fi, e0 + 2, n), c2 = ldi(ei, fi, (size_t)E + e0 + 2, n);
        int r3 = ldi(ei, fi, e0 + 3, n), c3 = ldi(ei, fi, (size_t)E + e0 + 3, n);
        int k0 = rank[e0], k1 = rank[e0 + 1], k2 = rank[e0 + 2], k3 = rank[e0 + 3];
        int p0 = rowptr[c0] + k0;
        int p1 = rowptr[c1] + k1;
        int p2 = rowptr[c2] + k2;
        int p3 = rowptr[c3] + k3;
        srcs[p0] = r0;
        srcs[p1] = r1;
        srcs[p2] = r2;
        srcs[p3] = r3;
    } else {
        for (int e = e0; e < E; ++e) {
            int r = ldi(ei, fi, e, n);
            int c = ldi(ei, fi, (size_t)E + e, n);
            srcs[rowptr[c] + rank[e]] = r;
        }
    }
}

// ---------------- fused node stage 1: gather xd + h1 MLP + y = dinv*xw2 ----------------
__global__ void k_node1(const float2* __restrict__ xd, const int* __restrict__ flags,
                        const float* __restrict__ dinv, const int* __restrict__ rowptr,
                        const int* __restrict__ srcs,
                        const void* __restrict__ W1, const void* __restrict__ b1,
                        const void* __restrict__ W2,
                        unsigned short* __restrict__ y, int n) {
    __shared__ float sW1[128];
    __shared__ float sb1[64];
    __shared__ float sW2[64 * 32];
    int tid = threadIdx.x;
    int fb = flags[0];
    for (int idx = tid; idx < 128; idx += blockDim.x) sW1[idx] = ldf(W1, fb, idx);
    for (int idx = tid; idx < 64; idx += blockDim.x)  sb1[idx] = ldf(b1, fb, idx);
    for (int idx = tid; idx < 64 * 32; idx += blockDim.x) sW2[idx] = ldf(W2, fb, idx);
    __syncthreads();
    int t = blockIdx.x * blockDim.x + tid;
    int i = t >> 5, lane = t & 31;
    if (i >= n) return;
    int start = rowptr[i], end = rowptr[i + 1];
    float di = dinv[i];
    float p0 = 0.f, p1 = 0.f;
    for (int m = start + lane; m < end; m += 32) {
        int r = srcs[m];
        float2 xv = xd[r];   // already dinv[r]*x[r]
        p0 += xv.x;
        p1 += xv.y;
    }
#pragma unroll
    for (int off = 16; off; off >>= 1) {
        p0 += __shfl_xor(p0, off, 32);
        p1 += __shfl_xor(p1, off, 32);
    }
    float2 xi = xd[i];       // dinv[i]*x[i] == self-loop term pre-factor
    float a0 = di * (p0 + xi.x);
    float a1 = di * (p1 + xi.y);
    int j = lane;
    float s = 0.f;
#pragma unroll 4
    for (int k = 0; k < 64; ++k) {
        float h = fmaxf(fmaf(a0, sW1[k], fmaf(a1, sW1[64 + k], sb1[k])), 0.f);
        s = fmaf(h, sW2[k * 32 + j], s);
    }
    float ys = di * s;  // premultiplied: gather-2 becomes pure adds
    y[t] = (unsigned short)(__float_as_uint(ys) >> 16);
}

// ---------------- layer-2 gather (pure adds on y) + edge-MLP first-layer hoist ----------------
__global__ void k_gather2q(const unsigned short* __restrict__ y, const int* __restrict__ flags,
                           const float* __restrict__ dinv, const int* __restrict__ rowptr,
                           const int* __restrict__ srcs, const void* __restrict__ b2v,
                           const void* __restrict__ Wm1, const void* __restrict__ bm1,
                           unsigned short* __restrict__ q1, unsigned short* __restrict__ q2, int n) {
    __shared__ float sW[64 * 16];   // Wm1 rows 0..63, row-major [row][j]
    __shared__ float sb1[16];
    __shared__ float sb2[32];
    int tid = threadIdx.x;
    int fb = flags[0];
    for (int idx = tid; idx < 64 * 16; idx += blockDim.x) sW[idx] = ldf(Wm1, fb, idx);
    if (tid < 16) sb1[tid] = ldf(bm1, fb, tid);
    if (tid >= 16 && tid < 48) sb2[tid - 16] = ldf(b2v, fb, tid - 16);
    __syncthreads();
    int t = blockIdx.x * blockDim.x + tid;
    int i = t >> 5, lane = t & 31;
    if (i >= n) return;
    float di = dinv[i];
    int start = rowptr[i], end = rowptr[i + 1];
    float acc = bf2f_bits(y[i * 32 + lane]);  // self term
    for (int base = start; base < end; base += 32) {
        int cnt = end - base; if (cnt > 32) cnt = 32;
        int sl = (lane < cnt) ? srcs[base + lane] : 0;  // one coalesced load / 32 nbrs
        int k = 0;
        for (; k + 4 <= cnt; k += 4) {
            int ra = __shfl(sl, k, 32),     rb = __shfl(sl, k + 1, 32);
            int rc = __shfl(sl, k + 2, 32), rd = __shfl(sl, k + 3, 32);
            float wa = bf2f_bits(y[ra * 32 + lane]);
            float wb = bf2f_bits(y[rb * 32 + lane]);
            float wc = bf2f_bits(y[rc * 32 + lane]);
            float wd = bf2f_bits(y[rd * 32 + lane]);
            acc += (wa + wb) + (wc + wd);
        }
        for (; k < cnt; ++k) {
            int rr = __shfl(sl, k, 32);
            acc += bf2f_bits(y[rr * 32 + lane]);
        }
    }
    float v = fmaxf(fmaf(di, acc, sb2[lane]), 0.f);   // h2[i][lane]

    int j = lane & 15;
    int half = lane >> 4;
    float q = half ? 0.f : sb1[j];
    const float* wbase = sW + half * (32 * 16);
#pragma unroll 8
    for (int k = 0; k < 32; ++k) {
        float h = __shfl(v, k, 32);
        q = fmaf(h, wbase[k * 16 + j], q);
    }
    unsigned short qb = f2f16b(q);
    if (half == 0) q1[i * 16 + j] = qb;
    else           q2[i * 16 + j] = qb;
}

// ---------------- edge MLP: 1 thread/edge on fp16 q-tables ----------------
__global__ void k_edge_mlp2(const int* __restrict__ ei, const int* __restrict__ flags,
                            const unsigned short* __restrict__ q1,
                            const unsigned short* __restrict__ q2,
                            const void* __restrict__ ea,
                            const void* __restrict__ Wm1, const void* __restrict__ Wm2,
                            const void* __restrict__ bm2,
                            void* __restrict__ out, int E, int n) {
    __shared__ __align__(16) float sWa[16];   // Wm1 row 64
    __shared__ __align__(16) float sWb[16];   // Wm1 row 65
    __shared__ __align__(16) float sW2[16];
    __shared__ float sB2;
    int tid = threadIdx.x;
    int fb = flags[0], fi = flags[1];
    if (tid < 16) sWa[tid] = ldf(Wm1, fb, 64 * 16 + tid);
    else if (tid < 32) sWb[tid - 16] = ldf(Wm1, fb, 65 * 16 + (tid - 16));
    else if (tid < 48) sW2[tid - 32] = ldf(Wm2, fb, tid - 32);
    else if (tid == 48) sB2 = ldf(bm2, fb, 0);
    __syncthreads();

    int e = blockIdx.x * blockDim.x + tid;
    if (e >= E) return;
    int r = ldi(ei, fi, e, n);
    int c = ldi(ei, fi, (size_t)E + e, n);
    float ea0 = ldf(ea, fb, 2 * (size_t)e), ea1 = ldf(ea, fb, 2 * (size_t)e + 1);

    const uint4* q1u = (const uint4*)q1;
    const uint4* q2u = (const uint4*)q2;
    uint4 A0 = q1u[r * 2], A1 = q1u[r * 2 + 1];
    uint4 B0 = q2u[c * 2], B1 = q2u[c * 2 + 1];

    float o = sB2;
#define E2(uA, uB, JA, JB)                                                          \
    {                                                                               \
        float h0 = f16b2f((unsigned short)((uA) & 0xffffu))                         \
                 + f16b2f((unsigned short)((uB) & 0xffffu))                         \
                 + ea0 * sWa[JA] + ea1 * sWb[JA];                                   \
        o = fmaf(fmaxf(h0, 0.f), sW2[JA], o);                                       \
        float h1 = f16b2f((unsigned short)((uA) >> 16))                             \
                 + f16b2f((unsigned short)((uB) >> 16))                             \
                 + ea0 * sWa[JB] + ea1 * sWb[JB];                                   \
        o = fmaf(fmaxf(h1, 0.f), sW2[JB], o);                                       \
    }
    E2(A0.x, B0.x, 0, 1)   E2(A0.y, B0.y, 2, 3)
    E2(A0.z, B0.z, 4, 5)   E2(A0.w, B0.w, 6, 7)
    E2(A1.x, B1.x, 8, 9)   E2(A1.y, B1.y, 10, 11)
    E2(A1.z, B1.z, 12, 13) E2(A1.w, B1.w, 14, 15)
#undef E2

    if (fb) ((bf16*)out)[e] = __float2bfloat16(o);
    else    ((float*)out)[e] = o;
}

extern "C" void kernel_launch(void* const* d_in, const int* in_sizes, int n_in,
                              void* d_out, int out_size, void* d_ws, size_t ws_size,
                              hipStream_t stream) {
    const void* x   = d_in[0];
    const int*  ei  = (const int*)d_in[1];
    const void* ea  = d_in[2];
    const void* W1  = d_in[3];
    const void* b1  = d_in[4];
    const void* W2  = d_in[5];
    const void* b2  = d_in[6];
    const void* Wm1 = d_in[7];
    const void* bm1 = d_in[8];
    const void* Wm2 = d_in[9];
    const void* bm2 = d_in[10];

    int n = in_sizes[0] / 2;   // x is [N,2]
    int E = in_sizes[2] / 2;   // edge_attr is [E,2]

    char* ws = (char*)d_ws;
    size_t off = 0;
    auto take = [&](size_t bytes) -> char* {
        char* p = ws + off;
        off += bytes;
        off = (off + 255) & ~(size_t)255;
        return p;
    };
    int* flags   = (int*)take(8);
    int* counts  = (int*)take((size_t)(n + 1) * 4);
    float* dinv  = (float*)take((size_t)n * 4);
    float2* xd   = (float2*)take((size_t)n * 8);
    int* rowptr  = (int*)take((size_t)(n + 1) * 4);
    int* chsum   = (int*)take(1024);
    int* srcs    = (int*)take((size_t)E * 4);
    unsigned short* y = (unsigned short*)take((size_t)n * 32 * 2);
    // union region: rank (E*4, used hist->fill) then q1|q2 (n*16*2 each, used after)
    size_t qbytes = (size_t)n * 16 * 2;
    size_t ubytes = (size_t)E * 4;
    if (ubytes < 2 * qbytes) ubytes = 2 * qbytes;
    char* un = take(ubytes);
    int* rank = (int*)un;
    unsigned short* q1 = (unsigned short*)un;
    unsigned short* q2 = (unsigned short*)(un + qbytes);

    if (off > ws_size) {
        int nf = out_size / 2;
        if (nf > 0) k_sentinel<<<(nf + 255) / 256, 256, 0, stream>>>((float*)d_out, nf);
        return;
    }

    const int B = 256;
    int nch = (n + 511) / 512;  // 196 <= 256
    int E4 = (E + 3) / 4;
    k_detect<<<1, 64, 0, stream>>>(x, ei, flags);
    k_zero<<<(n + 1 + B - 1) / B, B, 0, stream>>>(counts, n + 1);
    k_hist<<<(E4 + B - 1) / B, B, 0, stream>>>(ei, flags, counts, rank, E, n);
    k_scan1<<<nch, 512, 0, stream>>>(counts, rowptr, chsum, dinv, x, flags, xd, n);
    k_scan2<<<1, 256, 0, stream>>>(chsum, nch);
    k_scan3<<<nch, 512, 0, stream>>>(rowptr, chsum, n, E);
    k_fill<<<(E4 + B - 1) / B, B, 0, stream>>>(ei, flags, rowptr, rank, srcs, E, n);
    k_node1<<<((size_t)n * 32 + B - 1) / B, B, 0, stream>>>(xd, flags, dinv, rowptr, srcs,
                                                            W1, b1, W2, y, n);
    k_gather2q<<<((size_t)n * 32 + B - 1) / B, B, 0, stream>>>(y, flags, dinv, rowptr, srcs,
                                                               b2, Wm1, bm1, q1, q2, n);
    k_edge_mlp2<<<(E + B - 1) / B, B, 0, stream>>>(ei, flags, q1, q2, ea, Wm1, Wm2, bm2,
                                                   d_out, E, n);
}

// Round 12
// 322.824 us; speedup vs baseline: 2.8920x; 1.0056x over previous
//
#include <hip/hip_runtime.h>
#include <hip/hip_bf16.h>

typedef __hip_bfloat16 bf16;

// ---- adaptive loads: fb=1 -> bf16 data, fb=0 -> float32 data ----
__device__ __forceinline__ float ldf(const void* p, int fb, size_t i) {
    if (fb) {
        unsigned int u = ((const unsigned short*)p)[i];
        return __uint_as_float(u << 16);
    }
    return ((const float*)p)[i];
}
// fi=1 -> int64 underlying (read low word), fi=0 -> int32. Clamped to [0,n).
__device__ __forceinline__ int ldi(const int* p, int fi, size_t i, int n) {
    int v = fi ? p[2 * i] : p[i];
    return ((unsigned)v < (unsigned)n) ? v : 0;
}
__device__ __forceinline__ float bf2f_bits(unsigned short u) {
    return __uint_as_float(((unsigned int)u) << 16);
}
__device__ __forceinline__ float f16b2f(unsigned short u) {
    _Float16 h = __builtin_bit_cast(_Float16, u);
    return (float)h;
}
__device__ __forceinline__ unsigned short f2f16b(float f) {
    _Float16 h = (_Float16)f;
    return __builtin_bit_cast(unsigned short, h);
}

// ---------------- dtype detection (parallel: 64 lanes) ----------------
__global__ void k_detect(const void* x, const int* ei, int* flags) {
    int lane = threadIdx.x;  // 64 threads, 1 wave
    const unsigned short* u = (const unsigned short*)x;
    float v0 = bf2f_bits(u[2 * lane]);
    float v1 = bf2f_bits(u[2 * lane + 1]);
    unsigned long long m0 = __ballot(!(v0 > -64.f && v0 < 64.f));
    unsigned long long m1 = __ballot(!(v1 > -64.f && v1 < 64.f));
    unsigned long long mz = __ballot(ei[2 * lane + 1] != 0);
    if (lane == 0) {
        int bad = __popcll(m0) + __popcll(m1);
        flags[0] = (bad >= 4) ? 0 : 1;  // 1 = floats are bf16
        flags[1] = (mz == 0) ? 1 : 0;   // 1 = indices are int64
    }
}

__global__ void k_sentinel(float* out, int nfloats) {
    int i = blockIdx.x * blockDim.x + threadIdx.x;
    if (i < nfloats) out[i] = 1000.0f;
}

// ---------------- CSR build ----------------
__global__ void k_zero(int* p, int n1) {
    int i = blockIdx.x * blockDim.x + threadIdx.x;
    if (i < n1) p[i] = 0;
}

// Padded histogram: one counter per 64B line (countsP[c*16]) -> no line-lock
// sharing between different counters. Atomic return value is the edge's rank.
__global__ void k_hist(const int* __restrict__ ei, const int* __restrict__ flags,
                       int* countsP, int* __restrict__ rank, int E, int n) {
    int t = blockIdx.x * blockDim.x + threadIdx.x;
    int e0 = t * 4;
    if (e0 >= E) return;
    int fi = flags[1];
    if (e0 + 4 <= E) {
        int c0 = ldi(ei, fi, (size_t)E + e0, n);
        int c1 = ldi(ei, fi, (size_t)E + e0 + 1, n);
        int c2 = ldi(ei, fi, (size_t)E + e0 + 2, n);
        int c3 = ldi(ei, fi, (size_t)E + e0 + 3, n);
        int k0 = atomicAdd(&countsP[c0 * 16], 1);
        int k1 = atomicAdd(&countsP[c1 * 16], 1);
        int k2 = atomicAdd(&countsP[c2 * 16], 1);
        int k3 = atomicAdd(&countsP[c3 * 16], 1);
        rank[e0]     = k0;
        rank[e0 + 1] = k1;
        rank[e0 + 2] = k2;
        rank[e0 + 3] = k3;
    } else {
        for (int e = e0; e < E; ++e)
            rank[e] = atomicAdd(&countsP[ldi(ei, fi, (size_t)E + e, n) * 16], 1);
    }
}

// chunk = 512. scan1: per-chunk exclusive scan into rowptr; fused dinv + xd=dinv*x.
__global__ void k_scan1(const int* __restrict__ countsP, int* __restrict__ rowptr,
                        int* __restrict__ chsum, float* __restrict__ dinv,
                        const void* __restrict__ x, const int* __restrict__ flags,
                        float2* __restrict__ xd, int n) {
    __shared__ int s[512];
    int t = threadIdx.x, i = blockIdx.x * 512 + t;
    int v = (i < n) ? countsP[i * 16] : 0;
    if (i < n) {
        float di = rsqrtf((float)(v + 1));  // +1 self loop
        dinv[i] = di;
        int fb = flags[0];
        float2 o;
        o.x = di * ldf(x, fb, 2 * (size_t)i);
        o.y = di * ldf(x, fb, 2 * (size_t)i + 1);
        xd[i] = o;
    }
    s[t] = v;
    __syncthreads();
    for (int off = 1; off < 512; off <<= 1) {
        int add = (t >= off) ? s[t - off] : 0;
        __syncthreads();
        s[t] += add;
        __syncthreads();
    }
    if (i < n) rowptr[i] = s[t] - v;            // chunk-local exclusive
    if (t == 511) chsum[blockIdx.x] = s[511];   // chunk total
}

// scan2: one block scans <=256 chunk sums (exclusive, in place)
__global__ void k_scan2(int* chsum, int nch) {
    __shared__ int s[256];
    int t = threadIdx.x;
    int v = (t < nch) ? chsum[t] : 0;
    s[t] = v;
    __syncthreads();
    for (int off = 1; off < 256; off <<= 1) {
        int add = (t >= off) ? s[t - off] : 0;
        __syncthreads();
        s[t] += add;
        __syncthreads();
    }
    if (t < nch) chsum[t] = s[t] - v;           // exclusive
}

// scan3: add chunk offsets; rowptr[n]=E
__global__ void k_scan3(int* __restrict__ rowptr, const int* __restrict__ chsum,
                        int n, int E) {
    int t = threadIdx.x, i = blockIdx.x * 512 + t;
    if (i < n) rowptr[i] += chsum[blockIdx.x];
    if (blockIdx.x == 0 && t == 0) rowptr[n] = E;
}

// atomic-free fill: pos = rowptr[c] + rank[e]; 4 independent chains/thread.
__global__ void k_fill(const int* __restrict__ ei, const int* __restrict__ flags,
                       const int* __restrict__ rowptr, const int* __restrict__ rank,
                       int* __restrict__ srcs, int E, int n) {
    int t = blockIdx.x * blockDim.x + threadIdx.x;
    int e0 = t * 4;
    if (e0 >= E) return;
    int fi = flags[1];
    if (e0 + 4 <= E) {
        int r0 = ldi(ei, fi, e0, n),     c0 = ldi(ei, fi, (size_t)E + e0, n);
        int r1 = ldi(ei, fi, e0 + 1, n), c1 = ldi(ei, fi, (size_t)E + e0 + 1, n);
        int r2 = ldi(ei, fi, e0 + 2, n), c2 = ldi(ei, fi, (size_t)E + e0 + 2, n);
        int r3 = ldi(ei, fi, e0 + 3, n), c3 = ldi(ei, fi, (size_t)E + e0 + 3, n);
        int k0 = rank[e0], k1 = rank[e0 + 1], k2 = rank[e0 + 2], k3 = rank[e0 + 3];
        srcs[rowptr[c0] + k0] = r0;
        srcs[rowptr[c1] + k1] = r1;
        srcs[rowptr[c2] + k2] = r2;
        srcs[rowptr[c3] + k3] = r3;
    } else {
        for (int e = e0; e < E; ++e) {
            int r = ldi(ei, fi, e, n);
            int c = ldi(ei, fi, (size_t)E + e, n);
            srcs[rowptr[c] + rank[e]] = r;
        }
    }
}

// ---------------- fused node stage 1: gather xd + h1 MLP + y = dinv*xw2 ----------------
__global__ void k_node1(const float2* __restrict__ xd, const int* __restrict__ flags,
                        const float* __restrict__ dinv, const int* __restrict__ rowptr,
                        const int* __restrict__ srcs,
                        const void* __restrict__ W1, const void* __restrict__ b1,
                        const void* __restrict__ W2,
                        unsigned short* __restrict__ y, int n) {
    __shared__ float sW1[128];
    __shared__ float sb1[64];
    __shared__ float sW2[64 * 32];
    int tid = threadIdx.x;
    int fb = flags[0];
    for (int idx = tid; idx < 128; idx += blockDim.x) sW1[idx] = ldf(W1, fb, idx);
    for (int idx = tid; idx < 64; idx += blockDim.x)  sb1[idx] = ldf(b1, fb, idx);
    for (int idx = tid; idx < 64 * 32; idx += blockDim.x) sW2[idx] = ldf(W2, fb, idx);
    __syncthreads();
    int t = blockIdx.x * blockDim.x + tid;
    int i = t >> 5, lane = t & 31;
    if (i >= n) return;
    int start = rowptr[i], end = rowptr[i + 1];
    float di = dinv[i];
    float p0 = 0.f, p1 = 0.f;
    for (int m = start + lane; m < end; m += 32) {
        int r = srcs[m];
        float2 xv = xd[r];   // already dinv[r]*x[r]
        p0 += xv.x;
        p1 += xv.y;
    }
#pragma unroll
    for (int off = 16; off; off >>= 1) {
        p0 += __shfl_xor(p0, off, 32);
        p1 += __shfl_xor(p1, off, 32);
    }
    float2 xi = xd[i];       // dinv[i]*x[i] == self-loop term pre-factor
    float a0 = di * (p0 + xi.x);
    float a1 = di * (p1 + xi.y);
    int j = lane;
    float s = 0.f;
#pragma unroll 4
    for (int k = 0; k < 64; ++k) {
        float h = fmaxf(fmaf(a0, sW1[k], fmaf(a1, sW1[64 + k], sb1[k])), 0.f);
        s = fmaf(h, sW2[k * 32 + j], s);
    }
    float ys = di * s;  // premultiplied: gather-2 becomes pure adds
    y[t] = (unsigned short)(__float_as_uint(ys) >> 16);
}

// ---------------- layer-2 gather (pure adds on y) + edge-MLP first-layer hoist ----------------
__global__ void k_gather2q(const unsigned short* __restrict__ y, const int* __restrict__ flags,
                           const float* __restrict__ dinv, const int* __restrict__ rowptr,
                           const int* __restrict__ srcs, const void* __restrict__ b2v,
                           const void* __restrict__ Wm1, const void* __restrict__ bm1,
                           unsigned short* __restrict__ q1, unsigned short* __restrict__ q2, int n) {
    __shared__ float sW[64 * 16];   // Wm1 rows 0..63, row-major [row][j]
    __shared__ float sb1[16];
    __shared__ float sb2[32];
    int tid = threadIdx.x;
    int fb = flags[0];
    for (int idx = tid; idx < 64 * 16; idx += blockDim.x) sW[idx] = ldf(Wm1, fb, idx);
    if (tid < 16) sb1[tid] = ldf(bm1, fb, tid);
    if (tid >= 16 && tid < 48) sb2[tid - 16] = ldf(b2v, fb, tid - 16);
    __syncthreads();
    int t = blockIdx.x * blockDim.x + tid;
    int i = t >> 5, lane = t & 31;
    if (i >= n) return;
    float di = dinv[i];
    int start = rowptr[i], end = rowptr[i + 1];
    float acc = bf2f_bits(y[i * 32 + lane]);  // self term
    for (int base = start; base < end; base += 32) {
        int cnt = end - base; if (cnt > 32) cnt = 32;
        int sl = (lane < cnt) ? srcs[base + lane] : 0;  // one coalesced load / 32 nbrs
        int k = 0;
        for (; k + 4 <= cnt; k += 4) {
            int ra = __shfl(sl, k, 32),     rb = __shfl(sl, k + 1, 32);
            int rc = __shfl(sl, k + 2, 32), rd = __shfl(sl, k + 3, 32);
            float wa = bf2f_bits(y[ra * 32 + lane]);
            float wb = bf2f_bits(y[rb * 32 + lane]);
            float wc = bf2f_bits(y[rc * 32 + lane]);
            float wd = bf2f_bits(y[rd * 32 + lane]);
            acc += (wa + wb) + (wc + wd);
        }
        for (; k < cnt; ++k) {
            int rr = __shfl(sl, k, 32);
            acc += bf2f_bits(y[rr * 32 + lane]);
        }
    }
    float v = fmaxf(fmaf(di, acc, sb2[lane]), 0.f);   // h2[i][lane]

    int j = lane & 15;
    int half = lane >> 4;
    float q = half ? 0.f : sb1[j];
    const float* wbase = sW + half * (32 * 16);
#pragma unroll 8
    for (int k = 0; k < 32; ++k) {
        float h = __shfl(v, k, 32);
        q = fmaf(h, wbase[k * 16 + j], q);
    }
    unsigned short qb = f2f16b(q);
    if (half == 0) q1[i * 16 + j] = qb;
    else           q2[i * 16 + j] = qb;
}

// ---------------- edge MLP: 1 thread/edge on fp16 q-tables ----------------
__global__ void k_edge_mlp2(const int* __restrict__ ei, const int* __restrict__ flags,
                            const unsigned short* __restrict__ q1,
                            const unsigned short* __restrict__ q2,
                            const void* __restrict__ ea,
                            const void* __restrict__ Wm1, const void* __restrict__ Wm2,
                            const void* __restrict__ bm2,
                            void* __restrict__ out, int E, int n) {
    __shared__ __align__(16) float sWa[16];   // Wm1 row 64
    __shared__ __align__(16) float sWb[16];   // Wm1 row 65
    __shared__ __align__(16) float sW2[16];
    __shared__ float sB2;
    int tid = threadIdx.x;
    int fb = flags[0], fi = flags[1];
    if (tid < 16) sWa[tid] = ldf(Wm1, fb, 64 * 16 + tid);
    else if (tid < 32) sWb[tid - 16] = ldf(Wm1, fb, 65 * 16 + (tid - 16));
    else if (tid < 48) sW2[tid - 32] = ldf(Wm2, fb, tid - 32);
    else if (tid == 48) sB2 = ldf(bm2, fb, 0);
    __syncthreads();

    int e = blockIdx.x * blockDim.x + tid;
    if (e >= E) return;
    int r = ldi(ei, fi, e, n);
    int c = ldi(ei, fi, (size_t)E + e, n);
    float ea0 = ldf(ea, fb, 2 * (size_t)e), ea1 = ldf(ea, fb, 2 * (size_t)e + 1);

    const uint4* q1u = (const uint4*)q1;
    const uint4* q2u = (const uint4*)q2;
    uint4 A0 = q1u[r * 2], A1 = q1u[r * 2 + 1];
    uint4 B0 = q2u[c * 2], B1 = q2u[c * 2 + 1];

    float o = sB2;
#define E2(uA, uB, JA, JB)                                                          \
    {                                                                               \
        float h0 = f16b2f((unsigned short)((uA) & 0xffffu))                         \
                 + f16b2f((unsigned short)((uB) & 0xffffu))                         \
                 + ea0 * sWa[JA] + ea1 * sWb[JA];                                   \
        o = fmaf(fmaxf(h0, 0.f), sW2[JA], o);                                       \
        float h1 = f16b2f((unsigned short)((uA) >> 16))                             \
                 + f16b2f((unsigned short)((uB) >> 16))                             \
                 + ea0 * sWa[JB] + ea1 * sWb[JB];                                   \
        o = fmaf(fmaxf(h1, 0.f), sW2[JB], o);                                       \
    }
    E2(A0.x, B0.x, 0, 1)   E2(A0.y, B0.y, 2, 3)
    E2(A0.z, B0.z, 4, 5)   E2(A0.w, B0.w, 6, 7)
    E2(A1.x, B1.x, 8, 9)   E2(A1.y, B1.y, 10, 11)
    E2(A1.z, B1.z, 12, 13) E2(A1.w, B1.w, 14, 15)
#undef E2

    if (fb) ((bf16*)out)[e] = __float2bfloat16(o);
    else    ((float*)out)[e] = o;
}

extern "C" void kernel_launch(void* const* d_in, const int* in_sizes, int n_in,
                              void* d_out, int out_size, void* d_ws, size_t ws_size,
                              hipStream_t stream) {
    const void* x   = d_in[0];
    const int*  ei  = (const int*)d_in[1];
    const void* ea  = d_in[2];
    const void* W1  = d_in[3];
    const void* b1  = d_in[4];
    const void* W2  = d_in[5];
    const void* b2  = d_in[6];
    const void* Wm1 = d_in[7];
    const void* bm1 = d_in[8];
    const void* Wm2 = d_in[9];
    const void* bm2 = d_in[10];

    int n = in_sizes[0] / 2;   // x is [N,2]
    int E = in_sizes[2] / 2;   // edge_attr is [E,2]

    char* ws = (char*)d_ws;
    size_t off = 0;
    auto take = [&](size_t bytes) -> char* {
        char* p = ws + off;
        off += bytes;
        off = (off + 255) & ~(size_t)255;
        return p;
    };
    int* flags   = (int*)take(8);
    float* dinv  = (float*)take((size_t)n * 4);
    float2* xd   = (float2*)take((size_t)n * 8);
    int* rowptr  = (int*)take((size_t)(n + 1) * 4);
    int* chsum   = (int*)take(1024);
    // union A: padded counts (n*16*4, live zero->scan1) then srcs (E*4, live fill->gather2q)
    size_t aBytes = (size_t)n * 64;
    if (aBytes < (size_t)E * 4) aBytes = (size_t)E * 4;
    char* ua = take(aBytes);
    int* countsP = (int*)ua;
    int* srcs    = (int*)ua;
    unsigned short* y = (unsigned short*)take((size_t)n * 32 * 2);
    // union B: rank (E*4, live hist->fill) then q1|q2 (n*16*2 each, live after)
    size_t qbytes = (size_t)n * 16 * 2;
    size_t bBytes = (size_t)E * 4;
    if (bBytes < 2 * qbytes) bBytes = 2 * qbytes;
    char* ub = take(bBytes);
    int* rank = (int*)ub;
    unsigned short* q1 = (unsigned short*)ub;
    unsigned short* q2 = (unsigned short*)(ub + qbytes);

    if (off > ws_size) {
        int nf = out_size / 2;
        if (nf > 0) k_sentinel<<<(nf + 255) / 256, 256, 0, stream>>>((float*)d_out, nf);
        return;
    }

    const int B = 256;
    int nch = (n + 511) / 512;  // 196 <= 256
    int E4 = (E + 3) / 4;
    int nzero = n * 16;
    k_detect<<<1, 64, 0, stream>>>(x, ei, flags);
    k_zero<<<(nzero + B - 1) / B, B, 0, stream>>>(countsP, nzero);
    k_hist<<<(E4 + B - 1) / B, B, 0, stream>>>(ei, flags, countsP, rank, E, n);
    k_scan1<<<nch, 512, 0, stream>>>(countsP, rowptr, chsum, dinv, x, flags, xd, n);
    k_scan2<<<1, 256, 0, stream>>>(chsum, nch);
    k_scan3<<<nch, 512, 0, stream>>>(rowptr, chsum, n, E);
    k_fill<<<(E4 + B - 1) / B, B, 0, stream>>>(ei, flags, rowptr, rank, srcs, E, n);
    k_node1<<<((size_t)n * 32 + B - 1) / B, B, 0, stream>>>(xd, flags, dinv, rowptr, srcs,
                                                            W1, b1, W2, y, n);
    k_gather2q<<<((size_t)n * 32 + B - 1) / B, B, 0, stream>>>(y, flags, dinv, rowptr, srcs,
                                                               b2, Wm1, bm1, q1, q2, n);
    k_edge_mlp2<<<(E + B - 1) / B, B, 0, stream>>>(ei, flags, q1, q2, ea, Wm1, Wm2, bm2,
                                                   d_out, E, n);
}